// Round 4
// baseline (60.788 us; speedup 1.0000x reference)
//
#include <hip/hip_runtime.h>

// Fused two-stage grouped conv, (1,512,14,14) fp32.
// Stage 1: t4[k,o,m,n] = sum_{i<64,j<3} x[(i*8+o), (m+j-2) mod 14, n] * w1[k,i,j]
//          (term valid only when 0 <= m+j-1 < 14; mod-14 from roll(+1,H))
// Stage 2: out[i2*16+o2, m, n] = sum_{j<8,k<3} t4[o2,j,m,n+k-1] * w2[i2,j,k]  (zero-pad W)
//
// Latency-bound (14.5 MFLOP, 0.8 MB I/O). Block per (m,o2), 1024 threads.
// Stage-1 depth split 8-way with WAVE-UNIFORM groups (g = t>>7, readfirstlane)
// so w1 reads are scalar s_loads (no LDS, no ds_read in the hot chain); each
// lane issues only 24 independent global loads; 16 waves/CU hide latency.

__global__ __launch_bounds__(1024) void fused_shift_conv(
    const float* __restrict__ x,   // (512,14,14)
    const float* __restrict__ w1,  // (16,64,3)
    const float* __restrict__ w2,  // (32,8,3)
    float* __restrict__ out)       // (512,14,14)
{
    const int bx = blockIdx.x;     // 0..223
    const int m  = bx >> 4;        // 0..13
    const int o2 = bx & 15;        // 0..15  (== stage-1 output k)
    const int t  = threadIdx.x;    // 0..1023

    __shared__ float w2s[32 * 8 * 3];  // full w2
    __shared__ float t4p[8][112];      // stage-1 partials (i split 8-way)
    __shared__ float t4s[112];         // combined t4[o2, j(=o), m, n]

    // w2 staged by threads 768..959 (float4), overlapped with stage-1 compute
    if (t >= 768 && t < 768 + 192) {
        ((float4*)w2s)[t - 768] = ((const float4*)w2)[t - 768];
    }

    // ---- stage 1: 8*14 = 112 outputs, depth split 8-way (8 i's per group) ----
    const int g = __builtin_amdgcn_readfirstlane(t >> 7);  // 0..7, wave-uniform
    const int r = t & 127;
    if (r < 112) {
        const int o = r / 14;      // 0..7  (group channel -> stage-2 'j')
        const int n = r % 14;
        // global channel for (g,i,o): (g*8+i)*8 + o ; i in [0,8)
        const float* xg  = x  + (size_t)(g * 64 + o) * 196 + n;
        const float* w1g = w1 + o2 * 192 + g * 24;   // wave-uniform -> s_load
        float acc = 0.f;
        #pragma unroll
        for (int j = 0; j < 3; ++j) {
            const int hp = m + j - 1;              // padded-H index (block-uniform)
            if (hp >= 0 && hp < 14) {
                const int row = (hp + 13) % 14;    // undo roll(+1)
                const float* xp = xg + row * 14;
                #pragma unroll
                for (int i = 0; i < 8; ++i) {
                    acc += xp[(size_t)i * 8 * 196] * w1g[i * 3 + j];
                }
            }
        }
        t4p[g][r] = acc;
    }
    __syncthreads();

    if (t < 112) {
        float s = 0.f;
        #pragma unroll
        for (int g8 = 0; g8 < 8; ++g8) s += t4p[g8][t];
        t4s[t] = s;
    }
    __syncthreads();

    // ---- stage 2: 32*14 = 448 outputs, one per thread ----
    if (t < 448) {
        const int n  = t % 14;
        const int i2 = t / 14;   // 0..31
        const float* wp = w2s + i2 * 24;
        float acc = 0.f;
        #pragma unroll
        for (int j = 0; j < 8; ++j) {
            const float* tp = t4s + j * 14;
            #pragma unroll
            for (int k = 0; k < 3; ++k) {
                const int nn = n + k - 1;
                if (nn >= 0 && nn < 14) acc += tp[nn] * wp[j * 3 + k];
            }
        }
        out[((size_t)(i2 * 16 + o2) * 14 + m) * 14 + n] = acc;
    }
}

extern "C" void kernel_launch(void* const* d_in, const int* in_sizes, int n_in,
                              void* d_out, int out_size, void* d_ws, size_t ws_size,
                              hipStream_t stream) {
    const float* x  = (const float*)d_in[0];
    const float* w1 = (const float*)d_in[1];
    const float* w2 = (const float*)d_in[2];
    float* out = (float*)d_out;
    fused_shift_conv<<<dim3(224), dim3(1024), 0, stream>>>(x, w1, w2, out);
}